// Round 3
// baseline (1144.503 us; speedup 1.0000x reference)
//
#include <hip/hip_runtime.h>
#include <hip/hip_bf16.h>
#include <cfloat>

// Problem constants (match reference)
constexpr int NN = 50000;     // nodes
constexpr int EE = 400000;    // edges per type
constexpr int TT = 3;         // edge types
constexpr int D  = 256;       // feature dim (in == out)
constexpr int H  = 8;         // heads
constexpr int HD = 32;        // head dim
constexpr float NEG_SLOPE = 0.2f;

// ---------------------------------------------------------------------------
// zero helpers
__global__ void k_zero_i(int* __restrict__ p, int n) {
    int i = blockIdx.x * 256 + threadIdx.x;
    if (i < n) p[i] = 0;
}
__global__ void k_zero_f4(float4* __restrict__ p, int n4) {
    int i = blockIdx.x * 256 + threadIdx.x;
    if (i < n4) p[i] = make_float4(0.f, 0.f, 0.f, 0.f);
}

// ---------------------------------------------------------------------------
// K1: h = x @ Wt   (f32 tiled GEMM, 128x128 tile, 8x8 per thread), one type
__global__ __launch_bounds__(256) void k_gemm(
    const float* __restrict__ x, const float* __restrict__ Wt,
    float* __restrict__ ht) {
    const int bm = blockIdx.x * 128;
    const int bn = blockIdx.y * 128;

    __shared__ float As[8][128];
    __shared__ float Bs[8][128];

    const int tid = threadIdx.x;
    const int tx = tid & 15;   // col group 0..15
    const int ty = tid >> 4;   // row group 0..15

    float acc[8][8];
#pragma unroll
    for (int i = 0; i < 8; i++)
#pragma unroll
        for (int j = 0; j < 8; j++) acc[i][j] = 0.f;

    const int ar = tid >> 1;          // 0..127 (A tile row)
    const int ac = (tid & 1) * 4;     // 0 or 4 (A tile col)
    const int br = tid >> 5;          // 0..7   (B tile row)
    const int bc = (tid & 31) * 4;    // 0..124 (B tile col)

    for (int k0 = 0; k0 < D; k0 += 8) {
        const int gr = bm + ar;
        float4 av = make_float4(0.f, 0.f, 0.f, 0.f);
        if (gr < NN) av = *(const float4*)&x[(size_t)gr * D + k0 + ac];
        As[ac + 0][ar] = av.x;
        As[ac + 1][ar] = av.y;
        As[ac + 2][ar] = av.z;
        As[ac + 3][ar] = av.w;
        *(float4*)&Bs[br][bc] = *(const float4*)&Wt[(size_t)(k0 + br) * D + bn + bc];
        __syncthreads();
#pragma unroll
        for (int k = 0; k < 8; k++) {
            float a[8], b[8];
            *(float4*)&a[0] = *(float4*)&As[k][ty * 8];
            *(float4*)&a[4] = *(float4*)&As[k][ty * 8 + 4];
            *(float4*)&b[0] = *(float4*)&Bs[k][tx * 8];
            *(float4*)&b[4] = *(float4*)&Bs[k][tx * 8 + 4];
#pragma unroll
            for (int i = 0; i < 8; i++)
#pragma unroll
                for (int j = 0; j < 8; j++)
                    acc[i][j] = fmaf(a[i], b[j], acc[i][j]);
        }
        __syncthreads();
    }
#pragma unroll
    for (int i = 0; i < 8; i++) {
        const int gr = bm + ty * 8 + i;
        if (gr < NN) {
#pragma unroll
            for (int j0 = 0; j0 < 8; j0 += 4) {
                float4 v = make_float4(acc[i][j0], acc[i][j0 + 1],
                                       acc[i][j0 + 2], acc[i][j0 + 3]);
                *(float4*)&ht[(size_t)gr * D + bn + tx * 8 + j0] = v;
            }
        }
    }
}

// ---------------------------------------------------------------------------
// K2: per-(n,head) attention scores  sl = h . a_l,  sr = h . a_r  (one type)
__global__ __launch_bounds__(256) void k_scores(
    const float* __restrict__ h, const float* __restrict__ al_t,
    const float* __restrict__ ar_t, float* __restrict__ sl,
    float* __restrict__ sr) {
    const int id = blockIdx.x * 256 + threadIdx.x;  // n*H + head
    if (id >= NN * H) return;
    const int head = id & (H - 1);
    const int n = id >> 3;

    const float* hp = h + (size_t)n * D + head * HD;
    const float* al = al_t + head * HD;
    const float* ar = ar_t + head * HD;
    float accl = 0.f, accr = 0.f;
#pragma unroll
    for (int d = 0; d < HD; d += 4) {
        float4 hv = *(const float4*)&hp[d];
        float4 av = *(const float4*)&al[d];
        float4 bv = *(const float4*)&ar[d];
        accl += hv.x * av.x + hv.y * av.y + hv.z * av.z + hv.w * av.w;
        accr += hv.x * bv.x + hv.y * bv.y + hv.z * bv.z + hv.w * bv.w;
    }
    sl[id] = accl;
    sr[id] = accr;
}

// ---------------------------------------------------------------------------
// K3a: count in-degree per dst (one type; ei_t = edge_index[t], [2,E])
__global__ void k_count(const int* __restrict__ ei_t, int* __restrict__ cnt) {
    const int e = blockIdx.x * 256 + threadIdx.x;
    if (e >= EE) return;
    const int dst = ei_t[EE + e];
    atomicAdd(&cnt[dst], 1);
}

// K3b: exclusive scan (single block of 1024)
__global__ __launch_bounds__(1024) void k_scan(
    const int* __restrict__ cnt, int* __restrict__ offs,
    int* __restrict__ cursor) {
    const int tid = threadIdx.x;
    constexpr int CH = (NN + 1023) / 1024;  // 49
    const int lo = tid * CH;
    const int hi = min(NN, lo + CH);
    int s = 0;
    for (int i = lo; i < hi; i++) s += cnt[i];
    __shared__ int lds[1024];
    lds[tid] = s;
    __syncthreads();
    for (int off = 1; off < 1024; off <<= 1) {
        int v = (tid >= off) ? lds[tid - off] : 0;
        __syncthreads();
        lds[tid] += v;
        __syncthreads();
    }
    int run = lds[tid] - s;  // exclusive prefix
    for (int i = lo; i < hi; i++) {
        offs[i] = run;
        cursor[i] = run;
        run += cnt[i];
    }
    if (tid == 1023) offs[NN] = lds[1023];  // == EE
}

// K3c: scatter src ids into CSR slots
__global__ void k_scatter(const int* __restrict__ ei_t, int* __restrict__ cursor,
                          int* __restrict__ csr_src) {
    const int e = blockIdx.x * 256 + threadIdx.x;
    if (e >= EE) return;
    const int src = ei_t[e];
    const int dst = ei_t[EE + e];
    const int pos = atomicAdd(&cursor[dst], 1);
    csr_src[pos] = src;
}

// ---------------------------------------------------------------------------
// K4: per-dst fused segment softmax + aggregation + semantic-attention
//     accumulate. One wave per dst node. out[n,:] += att * gat_out[n,:]
__global__ __launch_bounds__(64) void k_aggregate(
    const float* __restrict__ h, const float* __restrict__ sl,
    const float* __restrict__ sr, const int* __restrict__ offs,
    const int* __restrict__ csr_src, const float* __restrict__ att_w,
    const float* __restrict__ att_b, float* __restrict__ out) {
    const int n = blockIdx.x;
    const int lane = threadIdx.x;
    const int start = offs[n];
    const int deg = offs[n + 1] - start;
    if (deg == 0) return;  // zero contribution (out pre-zeroed)

    float srv[8];
#pragma unroll
    for (int i = 0; i < 8; i += 4)
        *(float4*)&srv[i] = *(const float4*)&sr[(size_t)n * 8 + i];

    const int* srcs = csr_src + start;

    // pass 1: per-head max
    float m[8];
#pragma unroll
    for (int i = 0; i < 8; i++) m[i] = -FLT_MAX;
    for (int i = lane; i < deg; i += 64) {
        const int s = srcs[i];
        float v[8];
        *(float4*)&v[0] = *(const float4*)&sl[(size_t)s * 8];
        *(float4*)&v[4] = *(const float4*)&sl[(size_t)s * 8 + 4];
#pragma unroll
        for (int hh = 0; hh < 8; hh++) {
            float e = v[hh] + srv[hh];
            e = e >= 0.f ? e : NEG_SLOPE * e;
            m[hh] = fmaxf(m[hh], e);
        }
    }
#pragma unroll
    for (int hh = 0; hh < 8; hh++)
        for (int off = 32; off; off >>= 1)
            m[hh] = fmaxf(m[hh], __shfl_xor(m[hh], off, 64));

    // pass 2: per-head denom
    float dsum[8];
#pragma unroll
    for (int i = 0; i < 8; i++) dsum[i] = 0.f;
    for (int i = lane; i < deg; i += 64) {
        const int s = srcs[i];
        float v[8];
        *(float4*)&v[0] = *(const float4*)&sl[(size_t)s * 8];
        *(float4*)&v[4] = *(const float4*)&sl[(size_t)s * 8 + 4];
#pragma unroll
        for (int hh = 0; hh < 8; hh++) {
            float e = v[hh] + srv[hh];
            e = e >= 0.f ? e : NEG_SLOPE * e;
            dsum[hh] += __expf(e - m[hh]);
        }
    }
#pragma unroll
    for (int hh = 0; hh < 8; hh++)
        for (int off = 32; off; off >>= 1)
            dsum[hh] += __shfl_xor(dsum[hh], off, 64);
    float inv[8];
#pragma unroll
    for (int hh = 0; hh < 8; hh++) inv[hh] = 1.f / dsum[hh];

    // pass 3: weighted aggregation, chunked through LDS
    __shared__ float alds[64][8];
    __shared__ int slds[64];
    const int hd = lane >> 3;  // head of this lane's 4 output floats
    float4 acc = make_float4(0.f, 0.f, 0.f, 0.f);
    for (int base = 0; base < deg; base += 64) {
        const int nchunk = min(64, deg - base);
        if (lane < nchunk) {
            const int s = srcs[base + lane];
            slds[lane] = s;
            float v[8];
            *(float4*)&v[0] = *(const float4*)&sl[(size_t)s * 8];
            *(float4*)&v[4] = *(const float4*)&sl[(size_t)s * 8 + 4];
#pragma unroll
            for (int hh = 0; hh < 8; hh++) {
                float e = v[hh] + srv[hh];
                e = e >= 0.f ? e : NEG_SLOPE * e;
                alds[lane][hh] = __expf(e - m[hh]) * inv[hh];
            }
        }
        __syncthreads();
        for (int j = 0; j < nchunk; j++) {
            const int s = slds[j];
            const float a = alds[j][hd];
            float4 hv = *(const float4*)&h[(size_t)s * D + lane * 4];
            acc.x = fmaf(a, hv.x, acc.x);
            acc.y = fmaf(a, hv.y, acc.y);
            acc.z = fmaf(a, hv.z, acc.z);
            acc.w = fmaf(a, hv.w, acc.w);
        }
        __syncthreads();
    }

    // fused semantic attention: att = acc . att_w (wave reduce) + b
    float4 wv = *(const float4*)&att_w[lane * 4];
    float p = acc.x * wv.x + acc.y * wv.y + acc.z * wv.z + acc.w * wv.w;
#pragma unroll
    for (int off = 32; off; off >>= 1) p += __shfl_xor(p, off, 64);
    const float att = p + att_b[0];

    float* op = out + (size_t)n * D + lane * 4;
    float4 cur = *(float4*)op;
    cur.x = fmaf(att, acc.x, cur.x);
    cur.y = fmaf(att, acc.y, cur.y);
    cur.z = fmaf(att, acc.z, cur.z);
    cur.w = fmaf(att, acc.w, cur.w);
    *(float4*)op = cur;
}

// ---------------------------------------------------------------------------
extern "C" void kernel_launch(void* const* d_in, const int* in_sizes, int n_in,
                              void* d_out, int out_size, void* d_ws, size_t ws_size,
                              hipStream_t stream) {
    const float* x     = (const float*)d_in[0];
    const int*   ei    = (const int*)d_in[1];
    const float* W     = (const float*)d_in[2];
    const float* a_l   = (const float*)d_in[3];
    const float* a_r   = (const float*)d_in[4];
    const float* att_w = (const float*)d_in[5];
    const float* att_b = (const float*)d_in[6];
    float* out = (float*)d_out;

    // workspace layout (256B-aligned slices) — total ~57 MB
    char* ws = (char*)d_ws;
    size_t off = 0;
    auto alloc = [&](size_t bytes) {
        size_t cur = off;
        off += (bytes + 255) & ~(size_t)255;
        return cur;
    };
    float* h       = (float*)(ws + alloc((size_t)NN * D * 4));   // 51.2 MB
    float* sl      = (float*)(ws + alloc((size_t)NN * H * 4));   // 1.6 MB
    float* sr      = (float*)(ws + alloc((size_t)NN * H * 4));   // 1.6 MB
    int*   cnt     = (int*)(ws + alloc((size_t)NN * 4));
    int*   offs    = (int*)(ws + alloc((size_t)(NN + 1) * 4));
    int*   cursor  = (int*)(ws + alloc((size_t)NN * 4));
    int*   csr_src = (int*)(ws + alloc((size_t)EE * 4));
    (void)ws_size; (void)in_sizes; (void)n_in; (void)out_size;

    // zero the output accumulator (poisoned to 0xAA by harness)
    k_zero_f4<<<(NN * D / 4 + 255) / 256, 256, 0, stream>>>((float4*)out, NN * D / 4);

    dim3 ggrid((NN + 127) / 128, D / 128);
    for (int t = 0; t < TT; t++) {
        const float* Wt   = W + (size_t)t * D * D;
        const float* al_t = a_l + (size_t)t * H * HD;
        const float* ar_t = a_r + (size_t)t * H * HD;
        const int*   ei_t = ei + (size_t)t * 2 * EE;

        k_zero_i<<<(NN + 255) / 256, 256, 0, stream>>>(cnt, NN);
        k_gemm<<<ggrid, 256, 0, stream>>>(x, Wt, h);
        k_scores<<<(NN * H + 255) / 256, 256, 0, stream>>>(h, al_t, ar_t, sl, sr);
        k_count<<<(EE + 255) / 256, 256, 0, stream>>>(ei_t, cnt);
        k_scan<<<1, 1024, 0, stream>>>(cnt, offs, cursor);
        k_scatter<<<(EE + 255) / 256, 256, 0, stream>>>(ei_t, cursor, csr_src);
        k_aggregate<<<NN, 64, 0, stream>>>(h, sl, sr, offs, csr_src,
                                           att_w, att_b, out);
    }
}

// Round 4
// 978.122 us; speedup vs baseline: 1.1701x; 1.1701x over previous
//
#include <hip/hip_runtime.h>
#include <hip/hip_bf16.h>
#include <cfloat>

// Problem constants (match reference)
constexpr int NN = 50000;     // nodes
constexpr int EE = 400000;    // edges per type
constexpr int TT = 3;         // edge types
constexpr int D  = 256;       // feature dim (in == out)
constexpr int H  = 8;         // heads
constexpr int HD = 32;        // head dim
constexpr float NEG_SLOPE = 0.2f;

typedef __attribute__((ext_vector_type(8))) short short8;
typedef __attribute__((ext_vector_type(8))) unsigned short ushort8v;
typedef __attribute__((ext_vector_type(4))) float f32x4;

// f32 -> bf16 (RTNE) via bit ops (inputs are finite; no NaN handling needed)
__device__ __forceinline__ unsigned short f2bf(float f) {
    unsigned int b = __float_as_uint(f);
    b += 0x7FFFu + ((b >> 16) & 1u);
    return (unsigned short)(b >> 16);
}
__device__ __forceinline__ float bf2f(unsigned short u) {
    return __uint_as_float(((unsigned int)u) << 16);
}

// ---------------------------------------------------------------------------
// zero helpers
__global__ void k_zero_i(int* __restrict__ p, int n) {
    int i = blockIdx.x * 256 + threadIdx.x;
    if (i < n) p[i] = 0;
}
__global__ void k_zero_f4(float4* __restrict__ p, int n4) {
    int i = blockIdx.x * 256 + threadIdx.x;
    if (i < n4) p[i] = make_float4(0.f, 0.f, 0.f, 0.f);
}

// ---------------------------------------------------------------------------
// K-1: split W into bf16 hi/lo, TRANSPOSED to [t][n_out][k_in] for staging
__global__ void k_prepW(const float* __restrict__ W,
                        unsigned short* __restrict__ Whi,
                        unsigned short* __restrict__ Wlo) {
    int idx = blockIdx.x * 256 + threadIdx.x;  // over TT*D*D
    if (idx >= TT * D * D) return;
    int t = idx / (D * D);
    int rem = idx - t * (D * D);
    int k = rem >> 8;    // input dim (source row)
    int n = rem & 255;   // output dim (source col)
    float w = W[idx];
    unsigned short hi = f2bf(w);
    float lo = w - bf2f(hi);
    int didx = (t * D + n) * D + k;  // [t][n][k]
    Whi[didx] = hi;
    Wlo[didx] = f2bf(lo);
}

// ---------------------------------------------------------------------------
// K1: h = x @ Wt via bf16-split MFMA (3 terms: hi*hi + hi*lo + lo*hi).
// 128x128 tile, BK=32, 4 waves (2x2), each wave 64x64 = 4x4 fragments.
__global__ __launch_bounds__(256) void k_gemm_mfma(
    const float* __restrict__ x, const unsigned short* __restrict__ Whi_t,
    const unsigned short* __restrict__ Wlo_t, float* __restrict__ ht) {
    // padded stride 40 ushorts (80B): fragment reads ~conflict-free
    __shared__ unsigned short Ahi[128][40], Alo[128][40];
    __shared__ unsigned short Bhi[128][40], Blo[128][40];

    const int tid  = threadIdx.x;
    const int lane = tid & 63;
    const int wid  = tid >> 6;
    const int wm   = wid >> 1, wn = wid & 1;   // 2x2 wave grid
    const int bm   = blockIdx.x * 128, bn = blockIdx.y * 128;

    f32x4 acc[4][4];
#pragma unroll
    for (int m = 0; m < 4; m++)
#pragma unroll
        for (int n = 0; n < 4; n++) acc[m][n] = (f32x4){0.f, 0.f, 0.f, 0.f};

    for (int k0 = 0; k0 < D; k0 += 32) {
        // --- stage A: f32 x -> split bf16 hi/lo (reg-staged, padded LDS) ---
#pragma unroll
        for (int p = 0; p < 4; p++) {
            int s = p * 256 + tid;          // 1024 slots: 128 rows x 8 kq
            int row = s >> 3, kq = s & 7;   // kq*4 = k offset
            int grow = min(bm + row, NN - 1);
            float4 v = *(const float4*)&x[(size_t)grow * D + k0 + kq * 4];
            unsigned short h0 = f2bf(v.x), h1 = f2bf(v.y),
                           h2 = f2bf(v.z), h3 = f2bf(v.w);
            ushort4 hv = make_ushort4(h0, h1, h2, h3);
            ushort4 lv = make_ushort4(f2bf(v.x - bf2f(h0)), f2bf(v.y - bf2f(h1)),
                                      f2bf(v.z - bf2f(h2)), f2bf(v.w - bf2f(h3)));
            *(ushort4*)&Ahi[row][kq * 4] = hv;
            *(ushort4*)&Alo[row][kq * 4] = lv;
        }
        // --- stage B from pre-split transposed Wt [n][k] (bf16, L2-resident) ---
#pragma unroll
        for (int p = 0; p < 2; p++) {
            int s = p * 256 + tid;          // 512 slots: 128 n x 4 kq(8 k each)
            int nn = s >> 2, kq = s & 3;
            size_t soff = (size_t)(bn + nn) * D + k0 + kq * 8;
            ushort8v bh = *(const ushort8v*)&Whi_t[soff];
            ushort8v bl = *(const ushort8v*)&Wlo_t[soff];
            *(ushort8v*)&Bhi[nn][kq * 8] = bh;
            *(ushort8v*)&Blo[nn][kq * 8] = bl;
        }
        __syncthreads();

        // --- fragments: A row i=(lane&15), k = (lane>>4)*8 + e ---
        short8 ah[4], al[4], bh[4], bl[4];
        const int fr = lane & 15, fg = (lane >> 4) * 8;
#pragma unroll
        for (int m = 0; m < 4; m++) {
            ah[m] = *(const short8*)&Ahi[wm * 64 + m * 16 + fr][fg];
            al[m] = *(const short8*)&Alo[wm * 64 + m * 16 + fr][fg];
        }
#pragma unroll
        for (int n = 0; n < 4; n++) {
            bh[n] = *(const short8*)&Bhi[wn * 64 + n * 16 + fr][fg];
            bl[n] = *(const short8*)&Blo[wn * 64 + n * 16 + fr][fg];
        }
#pragma unroll
        for (int m = 0; m < 4; m++)
#pragma unroll
            for (int n = 0; n < 4; n++) {
                acc[m][n] = __builtin_amdgcn_mfma_f32_16x16x32_bf16(
                    ah[m], bh[n], acc[m][n], 0, 0, 0);
                acc[m][n] = __builtin_amdgcn_mfma_f32_16x16x32_bf16(
                    ah[m], bl[n], acc[m][n], 0, 0, 0);
                acc[m][n] = __builtin_amdgcn_mfma_f32_16x16x32_bf16(
                    al[m], bh[n], acc[m][n], 0, 0, 0);
            }
        __syncthreads();
    }

    // --- store C: D row = (lane>>4)*4 + r, col = lane&15 (verified m89/m91) ---
    const int cr = (lane >> 4) * 4, cc = lane & 15;
#pragma unroll
    for (int m = 0; m < 4; m++) {
#pragma unroll
        for (int r = 0; r < 4; r++) {
            int row = bm + wm * 64 + m * 16 + cr + r;
            if (row < NN) {
                float* dst = &ht[(size_t)row * D + bn + wn * 64 + cc];
#pragma unroll
                for (int n = 0; n < 4; n++) dst[n * 16] = acc[m][n][r];
            }
        }
    }
}

// ---------------------------------------------------------------------------
// K2: per-(n,head) attention scores  sl = h . a_l,  sr = h . a_r  (one type)
__global__ __launch_bounds__(256) void k_scores(
    const float* __restrict__ h, const float* __restrict__ al_t,
    const float* __restrict__ ar_t, float* __restrict__ sl,
    float* __restrict__ sr) {
    const int id = blockIdx.x * 256 + threadIdx.x;  // n*H + head
    if (id >= NN * H) return;
    const int head = id & (H - 1);
    const int n = id >> 3;

    const float* hp = h + (size_t)n * D + head * HD;
    const float* al = al_t + head * HD;
    const float* ar = ar_t + head * HD;
    float accl = 0.f, accr = 0.f;
#pragma unroll
    for (int d = 0; d < HD; d += 4) {
        float4 hv = *(const float4*)&hp[d];
        float4 av = *(const float4*)&al[d];
        float4 bv = *(const float4*)&ar[d];
        accl += hv.x * av.x + hv.y * av.y + hv.z * av.z + hv.w * av.w;
        accr += hv.x * bv.x + hv.y * bv.y + hv.z * bv.z + hv.w * bv.w;
    }
    sl[id] = accl;
    sr[id] = accr;
}

// ---------------------------------------------------------------------------
// K3a: count in-degree per dst (one type; ei_t = edge_index[t], [2,E])
__global__ void k_count(const int* __restrict__ ei_t, int* __restrict__ cnt) {
    const int e = blockIdx.x * 256 + threadIdx.x;
    if (e >= EE) return;
    const int dst = ei_t[EE + e];
    atomicAdd(&cnt[dst], 1);
}

// K3b: exclusive scan (single block of 1024)
__global__ __launch_bounds__(1024) void k_scan(
    const int* __restrict__ cnt, int* __restrict__ offs,
    int* __restrict__ cursor) {
    const int tid = threadIdx.x;
    constexpr int CH = (NN + 1023) / 1024;  // 49
    const int lo = tid * CH;
    const int hi = min(NN, lo + CH);
    int s = 0;
    for (int i = lo; i < hi; i++) s += cnt[i];
    __shared__ int lds[1024];
    lds[tid] = s;
    __syncthreads();
    for (int off = 1; off < 1024; off <<= 1) {
        int v = (tid >= off) ? lds[tid - off] : 0;
        __syncthreads();
        lds[tid] += v;
        __syncthreads();
    }
    int run = lds[tid] - s;  // exclusive prefix
    for (int i = lo; i < hi; i++) {
        offs[i] = run;
        cursor[i] = run;
        run += cnt[i];
    }
    if (tid == 1023) offs[NN] = lds[1023];  // == EE
}

// K3c: scatter src ids into CSR slots
__global__ void k_scatter(const int* __restrict__ ei_t, int* __restrict__ cursor,
                          int* __restrict__ csr_src) {
    const int e = blockIdx.x * 256 + threadIdx.x;
    if (e >= EE) return;
    const int src = ei_t[e];
    const int dst = ei_t[EE + e];
    const int pos = atomicAdd(&cursor[dst], 1);
    csr_src[pos] = src;
}

// ---------------------------------------------------------------------------
// K4: per-dst fused segment softmax + aggregation + semantic-attention
//     accumulate. One wave per dst node. out[n,:] += att * gat_out[n,:]
__global__ __launch_bounds__(64) void k_aggregate(
    const float* __restrict__ h, const float* __restrict__ sl,
    const float* __restrict__ sr, const int* __restrict__ offs,
    const int* __restrict__ csr_src, const float* __restrict__ att_w,
    const float* __restrict__ att_b, float* __restrict__ out) {
    const int n = blockIdx.x;
    const int lane = threadIdx.x;
    const int start = offs[n];
    const int deg = offs[n + 1] - start;
    if (deg == 0) return;  // zero contribution (out pre-zeroed)

    float srv[8];
#pragma unroll
    for (int i = 0; i < 8; i += 4)
        *(float4*)&srv[i] = *(const float4*)&sr[(size_t)n * 8 + i];

    const int* srcs = csr_src + start;

    // pass 1: per-head max
    float m[8];
#pragma unroll
    for (int i = 0; i < 8; i++) m[i] = -FLT_MAX;
    for (int i = lane; i < deg; i += 64) {
        const int s = srcs[i];
        float v[8];
        *(float4*)&v[0] = *(const float4*)&sl[(size_t)s * 8];
        *(float4*)&v[4] = *(const float4*)&sl[(size_t)s * 8 + 4];
#pragma unroll
        for (int hh = 0; hh < 8; hh++) {
            float e = v[hh] + srv[hh];
            e = e >= 0.f ? e : NEG_SLOPE * e;
            m[hh] = fmaxf(m[hh], e);
        }
    }
#pragma unroll
    for (int hh = 0; hh < 8; hh++)
        for (int off = 32; off; off >>= 1)
            m[hh] = fmaxf(m[hh], __shfl_xor(m[hh], off, 64));

    // pass 2: per-head denom
    float dsum[8];
#pragma unroll
    for (int i = 0; i < 8; i++) dsum[i] = 0.f;
    for (int i = lane; i < deg; i += 64) {
        const int s = srcs[i];
        float v[8];
        *(float4*)&v[0] = *(const float4*)&sl[(size_t)s * 8];
        *(float4*)&v[4] = *(const float4*)&sl[(size_t)s * 8 + 4];
#pragma unroll
        for (int hh = 0; hh < 8; hh++) {
            float e = v[hh] + srv[hh];
            e = e >= 0.f ? e : NEG_SLOPE * e;
            dsum[hh] += __expf(e - m[hh]);
        }
    }
#pragma unroll
    for (int hh = 0; hh < 8; hh++)
        for (int off = 32; off; off >>= 1)
            dsum[hh] += __shfl_xor(dsum[hh], off, 64);
    float inv[8];
#pragma unroll
    for (int hh = 0; hh < 8; hh++) inv[hh] = 1.f / dsum[hh];

    // pass 3: weighted aggregation, chunked through LDS
    __shared__ float alds[64][8];
    __shared__ int slds[64];
    const int hd = lane >> 3;  // head of this lane's 4 output floats
    float4 acc = make_float4(0.f, 0.f, 0.f, 0.f);
    for (int base = 0; base < deg; base += 64) {
        const int nchunk = min(64, deg - base);
        if (lane < nchunk) {
            const int s = srcs[base + lane];
            slds[lane] = s;
            float v[8];
            *(float4*)&v[0] = *(const float4*)&sl[(size_t)s * 8];
            *(float4*)&v[4] = *(const float4*)&sl[(size_t)s * 8 + 4];
#pragma unroll
            for (int hh = 0; hh < 8; hh++) {
                float e = v[hh] + srv[hh];
                e = e >= 0.f ? e : NEG_SLOPE * e;
                alds[lane][hh] = __expf(e - m[hh]) * inv[hh];
            }
        }
        __syncthreads();
        for (int j = 0; j < nchunk; j++) {
            const int s = slds[j];
            const float a = alds[j][hd];
            float4 hv = *(const float4*)&h[(size_t)s * D + lane * 4];
            acc.x = fmaf(a, hv.x, acc.x);
            acc.y = fmaf(a, hv.y, acc.y);
            acc.z = fmaf(a, hv.z, acc.z);
            acc.w = fmaf(a, hv.w, acc.w);
        }
        __syncthreads();
    }

    // fused semantic attention: att = acc . att_w (wave reduce) + b
    float4 wv = *(const float4*)&att_w[lane * 4];
    float p = acc.x * wv.x + acc.y * wv.y + acc.z * wv.z + acc.w * wv.w;
#pragma unroll
    for (int off = 32; off; off >>= 1) p += __shfl_xor(p, off, 64);
    const float att = p + att_b[0];

    float* op = out + (size_t)n * D + lane * 4;
    float4 cur = *(float4*)op;
    cur.x = fmaf(att, acc.x, cur.x);
    cur.y = fmaf(att, acc.y, cur.y);
    cur.z = fmaf(att, acc.z, cur.z);
    cur.w = fmaf(att, acc.w, cur.w);
    *(float4*)op = cur;
}

// ---------------------------------------------------------------------------
extern "C" void kernel_launch(void* const* d_in, const int* in_sizes, int n_in,
                              void* d_out, int out_size, void* d_ws, size_t ws_size,
                              hipStream_t stream) {
    const float* x     = (const float*)d_in[0];
    const int*   ei    = (const int*)d_in[1];
    const float* W     = (const float*)d_in[2];
    const float* a_l   = (const float*)d_in[3];
    const float* a_r   = (const float*)d_in[4];
    const float* att_w = (const float*)d_in[5];
    const float* att_b = (const float*)d_in[6];
    float* out = (float*)d_out;

    // workspace layout (256B-aligned slices) — total ~58.3 MB
    char* ws = (char*)d_ws;
    size_t off = 0;
    auto alloc = [&](size_t bytes) {
        size_t cur = off;
        off += (bytes + 255) & ~(size_t)255;
        return cur;
    };
    float* h       = (float*)(ws + alloc((size_t)NN * D * 4));   // 51.2 MB
    float* sl      = (float*)(ws + alloc((size_t)NN * H * 4));   // 1.6 MB
    float* sr      = (float*)(ws + alloc((size_t)NN * H * 4));   // 1.6 MB
    int*   cnt     = (int*)(ws + alloc((size_t)NN * 4));
    int*   offs    = (int*)(ws + alloc((size_t)(NN + 1) * 4));
    int*   cursor  = (int*)(ws + alloc((size_t)NN * 4));
    int*   csr_src = (int*)(ws + alloc((size_t)EE * 4));
    unsigned short* Whi = (unsigned short*)(ws + alloc((size_t)TT * D * D * 2));
    unsigned short* Wlo = (unsigned short*)(ws + alloc((size_t)TT * D * D * 2));
    (void)ws_size; (void)in_sizes; (void)n_in; (void)out_size;

    // zero output accumulator (poisoned to 0xAA) + prep split/transposed W
    k_zero_f4<<<(NN * D / 4 + 255) / 256, 256, 0, stream>>>((float4*)out, NN * D / 4);
    k_prepW<<<(TT * D * D + 255) / 256, 256, 0, stream>>>(W, Whi, Wlo);

    dim3 ggrid((NN + 127) / 128, D / 128);
    for (int t = 0; t < TT; t++) {
        const float* al_t = a_l + (size_t)t * H * HD;
        const float* ar_t = a_r + (size_t)t * H * HD;
        const int*   ei_t = ei + (size_t)t * 2 * EE;
        const unsigned short* Whi_t = Whi + (size_t)t * D * D;
        const unsigned short* Wlo_t = Wlo + (size_t)t * D * D;

        k_zero_i<<<(NN + 255) / 256, 256, 0, stream>>>(cnt, NN);
        k_gemm_mfma<<<ggrid, 256, 0, stream>>>(x, Whi_t, Wlo_t, h);
        k_scores<<<(NN * H + 255) / 256, 256, 0, stream>>>(h, al_t, ar_t, sl, sr);
        k_count<<<(EE + 255) / 256, 256, 0, stream>>>(ei_t, cnt);
        k_scan<<<1, 1024, 0, stream>>>(cnt, offs, cursor);
        k_scatter<<<(EE + 255) / 256, 256, 0, stream>>>(ei_t, cursor, csr_src);
        k_aggregate<<<NN, 64, 0, stream>>>(h, sl, sr, offs, csr_src,
                                           att_w, att_b, out);
    }
}

// Round 6
// 648.007 us; speedup vs baseline: 1.7662x; 1.5094x over previous
//
#include <hip/hip_runtime.h>
#include <hip/hip_bf16.h>
#include <cfloat>

// Problem constants (match reference)
constexpr int NN = 50000;     // nodes
constexpr int EE = 400000;    // edges per type
constexpr int TT = 3;         // edge types
constexpr int D  = 256;       // feature dim (in == out)
constexpr int H  = 8;         // heads
constexpr int HD = 32;        // head dim
constexpr float NEG_SLOPE = 0.2f;

constexpr int SCAN_CHUNK = 2048;                      // elems per scan block
constexpr int SCAN_NB = (NN + SCAN_CHUNK - 1) / SCAN_CHUNK;  // 25

typedef __attribute__((ext_vector_type(8))) short short8;
typedef __attribute__((ext_vector_type(8))) unsigned short ushort8v;
typedef __attribute__((ext_vector_type(4))) float f32x4;

// f32 -> bf16 (RTNE) via bit ops (inputs are finite; no NaN handling needed)
__device__ __forceinline__ unsigned short f2bf(float f) {
    unsigned int b = __float_as_uint(f);
    b += 0x7FFFu + ((b >> 16) & 1u);
    return (unsigned short)(b >> 16);
}
__device__ __forceinline__ float bf2f(unsigned short u) {
    return __uint_as_float(((unsigned int)u) << 16);
}

// ---------------------------------------------------------------------------
// zero helpers
__global__ void k_zero_i(int* __restrict__ p, int n) {
    int i = blockIdx.x * 256 + threadIdx.x;
    if (i < n) p[i] = 0;
}
__global__ void k_zero_f4(float4* __restrict__ p, int n4) {
    int i = blockIdx.x * 256 + threadIdx.x;
    if (i < n4) p[i] = make_float4(0.f, 0.f, 0.f, 0.f);
}

// ---------------------------------------------------------------------------
// K-1: split W into bf16 hi/lo, TRANSPOSED to [t][n_out][k_in] for staging
__global__ void k_prepW(const float* __restrict__ W,
                        unsigned short* __restrict__ Whi,
                        unsigned short* __restrict__ Wlo) {
    int idx = blockIdx.x * 256 + threadIdx.x;  // over TT*D*D
    if (idx >= TT * D * D) return;
    int t = idx / (D * D);
    int rem = idx - t * (D * D);
    int k = rem >> 8;    // input dim (source row)
    int n = rem & 255;   // output dim (source col)
    float w = W[idx];
    unsigned short hi = f2bf(w);
    float lo = w - bf2f(hi);
    int didx = (t * D + n) * D + k;  // [t][n][k]
    Whi[didx] = hi;
    Wlo[didx] = f2bf(lo);
}

// ---------------------------------------------------------------------------
// K1: h = x @ Wt via bf16-split MFMA (3 terms: hi*hi + hi*lo + lo*hi).
// 128x128 tile, BK=32, 4 waves (2x2), each wave 64x64 = 4x4 fragments.
__global__ __launch_bounds__(256) void k_gemm_mfma(
    const float* __restrict__ x, const unsigned short* __restrict__ Whi_t,
    const unsigned short* __restrict__ Wlo_t, float* __restrict__ ht) {
    // padded stride 40 ushorts (80B): fragment reads ~conflict-free
    __shared__ unsigned short Ahi[128][40], Alo[128][40];
    __shared__ unsigned short Bhi[128][40], Blo[128][40];

    const int tid  = threadIdx.x;
    const int lane = tid & 63;
    const int wid  = tid >> 6;
    const int wm   = wid >> 1, wn = wid & 1;   // 2x2 wave grid
    const int bm   = blockIdx.x * 128, bn = blockIdx.y * 128;

    f32x4 acc[4][4];
#pragma unroll
    for (int m = 0; m < 4; m++)
#pragma unroll
        for (int n = 0; n < 4; n++) acc[m][n] = (f32x4){0.f, 0.f, 0.f, 0.f};

    for (int k0 = 0; k0 < D; k0 += 32) {
        // --- stage A: f32 x -> split bf16 hi/lo (reg-staged, padded LDS) ---
#pragma unroll
        for (int p = 0; p < 4; p++) {
            int s = p * 256 + tid;          // 1024 slots: 128 rows x 8 kq
            int row = s >> 3, kq = s & 7;   // kq*4 = k offset
            int grow = min(bm + row, NN - 1);
            float4 v = *(const float4*)&x[(size_t)grow * D + k0 + kq * 4];
            unsigned short h0 = f2bf(v.x), h1 = f2bf(v.y),
                           h2 = f2bf(v.z), h3 = f2bf(v.w);
            ushort4 hv = make_ushort4(h0, h1, h2, h3);
            ushort4 lv = make_ushort4(f2bf(v.x - bf2f(h0)), f2bf(v.y - bf2f(h1)),
                                      f2bf(v.z - bf2f(h2)), f2bf(v.w - bf2f(h3)));
            *(ushort4*)&Ahi[row][kq * 4] = hv;
            *(ushort4*)&Alo[row][kq * 4] = lv;
        }
        // --- stage B from pre-split transposed Wt [n][k] (bf16, L2-resident) ---
#pragma unroll
        for (int p = 0; p < 2; p++) {
            int s = p * 256 + tid;          // 512 slots: 128 n x 4 kq(8 k each)
            int nn = s >> 2, kq = s & 3;
            size_t soff = (size_t)(bn + nn) * D + k0 + kq * 8;
            ushort8v bh = *(const ushort8v*)&Whi_t[soff];
            ushort8v bl = *(const ushort8v*)&Wlo_t[soff];
            *(ushort8v*)&Bhi[nn][kq * 8] = bh;
            *(ushort8v*)&Blo[nn][kq * 8] = bl;
        }
        __syncthreads();

        // --- fragments: A row i=(lane&15), k = (lane>>4)*8 + e ---
        short8 ah[4], al[4], bh[4], bl[4];
        const int fr = lane & 15, fg = (lane >> 4) * 8;
#pragma unroll
        for (int m = 0; m < 4; m++) {
            ah[m] = *(const short8*)&Ahi[wm * 64 + m * 16 + fr][fg];
            al[m] = *(const short8*)&Alo[wm * 64 + m * 16 + fr][fg];
        }
#pragma unroll
        for (int n = 0; n < 4; n++) {
            bh[n] = *(const short8*)&Bhi[wn * 64 + n * 16 + fr][fg];
            bl[n] = *(const short8*)&Blo[wn * 64 + n * 16 + fr][fg];
        }
#pragma unroll
        for (int m = 0; m < 4; m++)
#pragma unroll
            for (int n = 0; n < 4; n++) {
                acc[m][n] = __builtin_amdgcn_mfma_f32_16x16x32_bf16(
                    ah[m], bh[n], acc[m][n], 0, 0, 0);
                acc[m][n] = __builtin_amdgcn_mfma_f32_16x16x32_bf16(
                    ah[m], bl[n], acc[m][n], 0, 0, 0);
                acc[m][n] = __builtin_amdgcn_mfma_f32_16x16x32_bf16(
                    al[m], bh[n], acc[m][n], 0, 0, 0);
            }
        __syncthreads();
    }

    // --- store C: D row = (lane>>4)*4 + r, col = lane&15 (verified m89/m91) ---
    const int cr = (lane >> 4) * 4, cc = lane & 15;
#pragma unroll
    for (int m = 0; m < 4; m++) {
#pragma unroll
        for (int r = 0; r < 4; r++) {
            int row = bm + wm * 64 + m * 16 + cr + r;
            if (row < NN) {
                float* dst = &ht[(size_t)row * D + bn + wn * 64 + cc];
#pragma unroll
                for (int n = 0; n < 4; n++) dst[n * 16] = acc[m][n][r];
            }
        }
    }
}

// ---------------------------------------------------------------------------
// K2: per-(n,head) attention scores  sl = h . a_l,  sr = h . a_r  (one type)
__global__ __launch_bounds__(256) void k_scores(
    const float* __restrict__ h, const float* __restrict__ al_t,
    const float* __restrict__ ar_t, float* __restrict__ sl,
    float* __restrict__ sr) {
    const int id = blockIdx.x * 256 + threadIdx.x;  // n*H + head
    if (id >= NN * H) return;
    const int head = id & (H - 1);
    const int n = id >> 3;

    const float* hp = h + (size_t)n * D + head * HD;
    const float* al = al_t + head * HD;
    const float* ar = ar_t + head * HD;
    float accl = 0.f, accr = 0.f;
#pragma unroll
    for (int d = 0; d < HD; d += 4) {
        float4 hv = *(const float4*)&hp[d];
        float4 av = *(const float4*)&al[d];
        float4 bv = *(const float4*)&ar[d];
        accl += hv.x * av.x + hv.y * av.y + hv.z * av.z + hv.w * av.w;
        accr += hv.x * bv.x + hv.y * bv.y + hv.z * bv.z + hv.w * bv.w;
    }
    sl[id] = accl;
    sr[id] = accr;
}

// ---------------------------------------------------------------------------
// CSR build (all types at once)
// K3a: count in-degree per (t, dst)
__global__ void k_count(const int* __restrict__ ei, int* __restrict__ cnt) {
    const int id = blockIdx.x * 256 + threadIdx.x;
    if (id >= TT * EE) return;
    const int t = id / EE, e = id - t * EE;
    const int dst = ei[(size_t)t * 2 * EE + EE + e];
    atomicAdd(&cnt[t * NN + dst], 1);
}

// K3b-1: per-chunk sums. grid (SCAN_NB, TT), 512 threads, 4 elems/thread.
__global__ __launch_bounds__(512) void k_bsum(const int* __restrict__ cnt,
                                              int* __restrict__ bsum) {
    const int t = blockIdx.y, b = blockIdx.x, tid = threadIdx.x;
    const int base = b * SCAN_CHUNK + tid * 4;
    const int* c = cnt + t * NN;
    int s = 0;
    if (base + 3 < NN) {
        int4 v = *(const int4*)&c[base];
        s = v.x + v.y + v.z + v.w;
    } else {
        for (int i = 0; i < 4; i++) if (base + i < NN) s += c[base + i];
    }
#pragma unroll
    for (int off = 32; off; off >>= 1) s += __shfl_xor(s, off, 64);
    __shared__ int ws[8];
    if ((tid & 63) == 0) ws[tid >> 6] = s;
    __syncthreads();
    if (tid == 0) {
        int tot = 0;
#pragma unroll
        for (int i = 0; i < 8; i++) tot += ws[i];
        bsum[t * SCAN_NB + b] = tot;
    }
}

// K3b-2: exclusive scan of chunk sums; wave w handles type w (25 elems).
__global__ __launch_bounds__(192) void k_bscan(const int* __restrict__ bsum,
                                               int* __restrict__ boff) {
    const int t = threadIdx.x >> 6;
    const int lane = threadIdx.x & 63;
    int orig = (lane < SCAN_NB) ? bsum[t * SCAN_NB + lane] : 0;
    int v = orig;
#pragma unroll
    for (int off = 1; off < 32; off <<= 1) {
        int u = __shfl_up(v, off, 64);
        if (lane >= off) v += u;
    }
    if (lane < SCAN_NB) boff[t * SCAN_NB + lane] = v - orig;  // exclusive
}

// K3b-3: within-chunk scan + chunk offset -> offs, cursor. grid (SCAN_NB, TT).
__global__ __launch_bounds__(512) void k_scan_add(
    const int* __restrict__ cnt, const int* __restrict__ boff,
    int* __restrict__ offs, int* __restrict__ cursor) {
    const int t = blockIdx.y, b = blockIdx.x, tid = threadIdx.x;
    const int base = b * SCAN_CHUNK + tid * 4;
    const int* c = cnt + t * NN;
    int v[4] = {0, 0, 0, 0};
    if (base + 3 < NN) {
        int4 q = *(const int4*)&c[base];
        v[0] = q.x; v[1] = q.y; v[2] = q.z; v[3] = q.w;
    } else {
        for (int i = 0; i < 4; i++) if (base + i < NN) v[i] = c[base + i];
    }
    const int s = v[0] + v[1] + v[2] + v[3];
    const int lane = tid & 63, wv = tid >> 6;
    int ps = s;
#pragma unroll
    for (int off = 1; off < 64; off <<= 1) {
        int u = __shfl_up(ps, off, 64);
        if (lane >= off) ps += u;
    }
    __shared__ int wsum[8];
    if (lane == 63) wsum[wv] = ps;
    __syncthreads();
    int woff = 0;
    for (int i = 0; i < wv; i++) woff += wsum[i];
    int run = boff[t * SCAN_NB + b] + woff + (ps - s);
    int* o = offs + t * (NN + 1);
    int* cur = cursor + t * NN;
    for (int i = 0; i < 4; i++) {
        const int idx = base + i;
        if (idx < NN) { o[idx] = run; cur[idx] = run; run += v[i]; }
    }
    if (b == 0 && tid == 0) o[NN] = EE;  // total per type is exactly EE
}

// K3c: scatter src ids into CSR slots (all types)
__global__ void k_scatter(const int* __restrict__ ei, int* __restrict__ cursor,
                          int* __restrict__ csr_src) {
    const int id = blockIdx.x * 256 + threadIdx.x;
    if (id >= TT * EE) return;
    const int t = id / EE, e = id - t * EE;
    const int src = ei[(size_t)t * 2 * EE + e];
    const int dst = ei[(size_t)t * 2 * EE + EE + e];
    const int pos = atomicAdd(&cursor[t * NN + dst], 1);
    csr_src[(size_t)t * EE + pos] = src;
}

// ---------------------------------------------------------------------------
// K4: per-dst fused segment softmax + aggregation + semantic-attention
//     accumulate. One wave per dst node. out[n,:] += att * gat_out[n,:]
__global__ __launch_bounds__(64) void k_aggregate(
    const float* __restrict__ h, const float* __restrict__ sl,
    const float* __restrict__ sr, const int* __restrict__ offs,
    const int* __restrict__ csr_src, const float* __restrict__ att_w,
    const float* __restrict__ att_b, float* __restrict__ out) {
    const int n = blockIdx.x;
    const int lane = threadIdx.x;
    const int start = offs[n];
    const int deg = offs[n + 1] - start;
    if (deg == 0) return;  // zero contribution (out pre-zeroed)

    float srv[8];
#pragma unroll
    for (int i = 0; i < 8; i += 4)
        *(float4*)&srv[i] = *(const float4*)&sr[(size_t)n * 8 + i];

    const int* srcs = csr_src + start;

    // pass 1: per-head max
    float m[8];
#pragma unroll
    for (int i = 0; i < 8; i++) m[i] = -FLT_MAX;
    for (int i = lane; i < deg; i += 64) {
        const int s = srcs[i];
        float v[8];
        *(float4*)&v[0] = *(const float4*)&sl[(size_t)s * 8];
        *(float4*)&v[4] = *(const float4*)&sl[(size_t)s * 8 + 4];
#pragma unroll
        for (int hh = 0; hh < 8; hh++) {
            float e = v[hh] + srv[hh];
            e = e >= 0.f ? e : NEG_SLOPE * e;
            m[hh] = fmaxf(m[hh], e);
        }
    }
#pragma unroll
    for (int hh = 0; hh < 8; hh++)
        for (int off = 32; off; off >>= 1)
            m[hh] = fmaxf(m[hh], __shfl_xor(m[hh], off, 64));

    // pass 2: per-head denom
    float dsum[8];
#pragma unroll
    for (int i = 0; i < 8; i++) dsum[i] = 0.f;
    for (int i = lane; i < deg; i += 64) {
        const int s = srcs[i];
        float v[8];
        *(float4*)&v[0] = *(const float4*)&sl[(size_t)s * 8];
        *(float4*)&v[4] = *(const float4*)&sl[(size_t)s * 8 + 4];
#pragma unroll
        for (int hh = 0; hh < 8; hh++) {
            float e = v[hh] + srv[hh];
            e = e >= 0.f ? e : NEG_SLOPE * e;
            dsum[hh] += __expf(e - m[hh]);
        }
    }
#pragma unroll
    for (int hh = 0; hh < 8; hh++)
        for (int off = 32; off; off >>= 1)
            dsum[hh] += __shfl_xor(dsum[hh], off, 64);
    float inv[8];
#pragma unroll
    for (int hh = 0; hh < 8; hh++) inv[hh] = 1.f / dsum[hh];

    // pass 3: weighted aggregation, chunked through LDS
    __shared__ float alds[64][8];
    __shared__ int slds[64];
    const int hd = lane >> 3;  // head of this lane's 4 output floats
    float4 acc = make_float4(0.f, 0.f, 0.f, 0.f);
    for (int base = 0; base < deg; base += 64) {
        const int nchunk = min(64, deg - base);
        if (lane < nchunk) {
            const int s = srcs[base + lane];
            slds[lane] = s;
            float v[8];
            *(float4*)&v[0] = *(const float4*)&sl[(size_t)s * 8];
            *(float4*)&v[4] = *(const float4*)&sl[(size_t)s * 8 + 4];
#pragma unroll
            for (int hh = 0; hh < 8; hh++) {
                float e = v[hh] + srv[hh];
                e = e >= 0.f ? e : NEG_SLOPE * e;
                alds[lane][hh] = __expf(e - m[hh]) * inv[hh];
            }
        }
        __syncthreads();
        for (int j = 0; j < nchunk; j++) {
            const int s = slds[j];
            const float a = alds[j][hd];
            float4 hv = *(const float4*)&h[(size_t)s * D + lane * 4];
            acc.x = fmaf(a, hv.x, acc.x);
            acc.y = fmaf(a, hv.y, acc.y);
            acc.z = fmaf(a, hv.z, acc.z);
            acc.w = fmaf(a, hv.w, acc.w);
        }
        __syncthreads();
    }

    // fused semantic attention: att = acc . att_w (wave reduce) + b
    float4 wv = *(const float4*)&att_w[lane * 4];
    float p = acc.x * wv.x + acc.y * wv.y + acc.z * wv.z + acc.w * wv.w;
#pragma unroll
    for (int off = 32; off; off >>= 1) p += __shfl_xor(p, off, 64);
    const float att = p + att_b[0];

    float* op = out + (size_t)n * D + lane * 4;
    float4 cur = *(float4*)op;
    cur.x = fmaf(att, acc.x, cur.x);
    cur.y = fmaf(att, acc.y, cur.y);
    cur.z = fmaf(att, acc.z, cur.z);
    cur.w = fmaf(att, acc.w, cur.w);
    *(float4*)op = cur;
}

// ---------------------------------------------------------------------------
extern "C" void kernel_launch(void* const* d_in, const int* in_sizes, int n_in,
                              void* d_out, int out_size, void* d_ws, size_t ws_size,
                              hipStream_t stream) {
    const float* x     = (const float*)d_in[0];
    const int*   ei    = (const int*)d_in[1];
    const float* W     = (const float*)d_in[2];
    const float* a_l   = (const float*)d_in[3];
    const float* a_r   = (const float*)d_in[4];
    const float* att_w = (const float*)d_in[5];
    const float* att_b = (const float*)d_in[6];
    float* out = (float*)d_out;

    // workspace layout (256B-aligned slices) — total ~62 MB
    char* ws = (char*)d_ws;
    size_t off = 0;
    auto alloc = [&](size_t bytes) {
        size_t cur = off;
        off += (bytes + 255) & ~(size_t)255;
        return cur;
    };
    float* h       = (float*)(ws + alloc((size_t)NN * D * 4));        // 51.2 MB
    float* sl      = (float*)(ws + alloc((size_t)NN * H * 4));        // 1.6 MB
    float* sr      = (float*)(ws + alloc((size_t)NN * H * 4));        // 1.6 MB
    int*   cnt     = (int*)(ws + alloc((size_t)TT * NN * 4));         // 0.6 MB
    int*   offs    = (int*)(ws + alloc((size_t)TT * (NN + 1) * 4));   // 0.6 MB
    int*   cursor  = (int*)(ws + alloc((size_t)TT * NN * 4));         // 0.6 MB
    int*   csr_src = (int*)(ws + alloc((size_t)TT * EE * 4));         // 4.8 MB
    int*   bsum    = (int*)(ws + alloc((size_t)TT * SCAN_NB * 4));
    int*   boff    = (int*)(ws + alloc((size_t)TT * SCAN_NB * 4));
    unsigned short* Whi = (unsigned short*)(ws + alloc((size_t)TT * D * D * 2));
    unsigned short* Wlo = (unsigned short*)(ws + alloc((size_t)TT * D * D * 2));
    (void)ws_size; (void)in_sizes; (void)n_in; (void)out_size;

    // zero output accumulator (poisoned to 0xAA) + prep split/transposed W
    k_zero_f4<<<(NN * D / 4 + 255) / 256, 256, 0, stream>>>((float4*)out, NN * D / 4);
    k_prepW<<<(TT * D * D + 255) / 256, 256, 0, stream>>>(W, Whi, Wlo);

    // CSR build for all 3 types (once, multi-block scan)
    k_zero_i<<<(TT * NN + 255) / 256, 256, 0, stream>>>(cnt, TT * NN);
    k_count<<<(TT * EE + 255) / 256, 256, 0, stream>>>(ei, cnt);
    k_bsum<<<dim3(SCAN_NB, TT), 512, 0, stream>>>(cnt, bsum);
    k_bscan<<<1, 192, 0, stream>>>(bsum, boff);
    k_scan_add<<<dim3(SCAN_NB, TT), 512, 0, stream>>>(cnt, boff, offs, cursor);
    k_scatter<<<(TT * EE + 255) / 256, 256, 0, stream>>>(ei, cursor, csr_src);

    dim3 ggrid((NN + 127) / 128, D / 128);
    for (int t = 0; t < TT; t++) {
        const float* al_t = a_l + (size_t)t * H * HD;
        const float* ar_t = a_r + (size_t)t * H * HD;
        const unsigned short* Whi_t = Whi + (size_t)t * D * D;
        const unsigned short* Wlo_t = Wlo + (size_t)t * D * D;

        k_gemm_mfma<<<ggrid, 256, 0, stream>>>(x, Whi_t, Wlo_t, h);
        k_scores<<<(NN * H + 255) / 256, 256, 0, stream>>>(h, al_t, ar_t, sl, sr);
        k_aggregate<<<NN, 64, 0, stream>>>(h, sl, sr, offs + (size_t)t * (NN + 1),
                                           csr_src + (size_t)t * EE,
                                           att_w, att_b, out);
    }
}